// Round 7
// baseline (512.174 us; speedup 1.0000x reference)
//
#include <hip/hip_runtime.h>

#define NN 50000
#define HD 128
#define NL 4
#define BN_EPS 1e-5f
#define NTILES 3125
#define MAXDEG 64
#define SBIN 64

typedef __attribute__((ext_vector_type(8))) short short8;
typedef __attribute__((ext_vector_type(4))) float f32x4;
typedef __attribute__((ext_vector_type(4))) uint uint4v;

__device__ inline ushort f2bf(float f){
  uint u = __float_as_uint(f);
  uint r = (u + 0x7fffu + ((u >> 16) & 1u)) >> 16;
  return (ushort)r;
}
__device__ inline float bflo(uint u){ return __uint_as_float(u << 16); }
__device__ inline float bfhi(uint u){ return __uint_as_float(u & 0xffff0000u); }
__device__ inline uint pk2(float lo, float hi){
  return (uint)f2bf(lo) | ((uint)f2bf(hi) << 16);
}

// ---------------- fused cast fp32 -> bf16 : x (sliced layout) then all weights ----
// x output layout: xs[slice][node][32ch], slice = ch>>5 (4 slices of 32 channels)
__global__ __launch_bounds__(256) void cast_all(const float* __restrict__ x,
                                                const float* __restrict__ w1,
                                                const float* __restrict__ w2,
                                                const float* __restrict__ wf,
                                                ushort* __restrict__ xs,
                                                ushort* __restrict__ wb){
  const int NX = NN * HD / 4;          // 1,600,000 float4-groups of x
  const int NT = NX + 36864;           // + weights
  int i = blockIdx.x * 256 + threadIdx.x;
  int stride = gridDim.x * 256;
  for (; i < NT; i += stride){
    const float* src; ushort* dst;
    if (i < NX){
      int node = i >> 5;
      int c0 = (i & 31) * 4;
      src = x + i * 4;
      dst = xs + ((c0 >> 5) * NN + node) * 32 + (c0 & 31);
    } else {
      int k = i - NX;
      dst = wb + k * 4;
      if (k < 16384)      src = w1 + k * 4;
      else if (k < 32768) src = w2 + (k - 16384) * 4;
      else                src = wf + (k - 32768) * 4;
    }
    float4 v = *(const float4*)src;
    ushort4 r;
    r.x = f2bf(v.x); r.y = f2bf(v.y); r.z = f2bf(v.z); r.w = f2bf(v.w);
    *(ushort4*)dst = r;
  }
}

// ---------------- bucketed CSR build (no scan) ----------------
__global__ void fill1_kernel(const int* __restrict__ dst, int* __restrict__ cnt,
                             int* __restrict__ pos, int E){
  int e = (blockIdx.x * 256 + threadIdx.x) * 4;
  if (e + 4 <= E){
    int4 d = *(const int4*)(dst + e);
    int4 p;
    p.x = atomicAdd(&cnt[d.x], 1);
    p.y = atomicAdd(&cnt[d.y], 1);
    p.z = atomicAdd(&cnt[d.z], 1);
    p.w = atomicAdd(&cnt[d.w], 1);
    *(int4*)(pos + e) = p;
  } else {
    for (; e < E; ++e) pos[e] = atomicAdd(&cnt[dst[e]], 1);
  }
}

__global__ void fill2_kernel(const int* __restrict__ src, const int* __restrict__ dst,
                             const int* __restrict__ pos, int* __restrict__ slots, int E){
  int e = (blockIdx.x * 256 + threadIdx.x) * 4;
  if (e + 4 <= E){
    int4 d = *(const int4*)(dst + e);
    int4 p = *(const int4*)(pos + e);
    int4 s = *(const int4*)(src + e);
    slots[d.x * MAXDEG + p.x] = s.x;
    slots[d.y * MAXDEG + p.y] = s.y;
    slots[d.z * MAXDEG + p.z] = s.z;
    slots[d.w * MAXDEG + p.w] = s.w;
  } else {
    for (; e < E; ++e) slots[dst[e] * MAXDEG + pos[e]] = src[e];
  }
}

// ---------------- BN param computation (device helper, threads<128) ----------------
// stats stored as SBIN sub-accumulators of 256 floats each (sum | sumsq)
__device__ inline void bn_params(const float* __restrict__ st, const float* __restrict__ gA,
                                 const float* __restrict__ gB, const float* __restrict__ bB,
                                 int mode, float* sS, float* sT){
  int c = threadIdx.x;
  if (c < 128){
    float s0 = 0.f, s1 = 0.f;
#pragma unroll 8
    for (int k = 0; k < SBIN; ++k){
      s0 += st[k * 256 + c];
      s1 += st[k * 256 + 128 + c];
    }
    const float invN = 1.f / (float)NN;
    float mu = s0 * invN;
    float var = fmaxf(s1 * invN - mu * mu, 0.f);
    float S, T;
    if (mode == 0){
      S = gA[c] * rsqrtf(var + BN_EPS);
      T = gB[c] - mu * S;
    } else {
      float inv2 = rsqrtf(var + BN_EPS);
      float tt = gA[c] * inv2;
      float inv3 = rsqrtf(tt * tt * var + BN_EPS);
      S = tt * inv3 * gB[c];
      T = bB[c] - mu * S;
    }
    sS[c] = S; sT[c] = T;
  }
}

// ---------------- sliced aggregation: hs[s] = aff(x_self) + sum(aff(x_neigh)) ----
// slice = blockIdx&3 (pins slice->XCD under round-robin dispatch: per-XCD L2 holds
// one full 3.2MB x-slice -> gather becomes L2-hit). 4-lane group per node (64B
// row-slice = 4 x dwordx4), 64 nodes/block, grid 782*4.
template<bool AFF>
__global__ __launch_bounds__(256) void aggs_t(const ushort* __restrict__ xs,
                                              const int* __restrict__ deg,
                                              const int* __restrict__ slots,
                                              const float* __restrict__ statsIn,
                                              const float* __restrict__ g2,
                                              const float* __restrict__ g3,
                                              const float* __restrict__ b3,
                                              ushort* __restrict__ hs){
  __shared__ float sS[128];
  __shared__ float sT[128];
  if (AFF){
    bn_params(statsIn, g2, g3, b3, 1, sS, sT);
    __syncthreads();
  }
  int slice = blockIdx.x & 3;
  int nb    = blockIdx.x >> 2;
  int gid   = threadIdx.x >> 2;    // group 0..63 (one node each)
  int li    = threadIdx.x & 3;     // 16B chunk within the 64B row-slice
  int node  = nb * 64 + gid;
  if (node >= NN) return;

  float S[8], T[8];
  if (AFF){
    int cb = slice * 32 + li * 8;
#pragma unroll
    for (int k = 0; k < 8; ++k){ S[k] = sS[cb + k]; T[k] = sT[cb + k]; }
  }

  const uint4v* x4 = (const uint4v*)xs;
  const int base = slice * (NN * 4);
  int e = deg[node];
  const int* sl = slots + node * MAXDEG;

  float a[8];
#define UNPK(v)                                                                  \
  if (AFF){                                                                      \
    a[0]+=fmaxf(bflo((v).x)*S[0]+T[0],0.f); a[1]+=fmaxf(bfhi((v).x)*S[1]+T[1],0.f); \
    a[2]+=fmaxf(bflo((v).y)*S[2]+T[2],0.f); a[3]+=fmaxf(bfhi((v).y)*S[3]+T[3],0.f); \
    a[4]+=fmaxf(bflo((v).z)*S[4]+T[4],0.f); a[5]+=fmaxf(bfhi((v).z)*S[5]+T[5],0.f); \
    a[6]+=fmaxf(bflo((v).w)*S[6]+T[6],0.f); a[7]+=fmaxf(bfhi((v).w)*S[7]+T[7],0.f); \
  } else {                                                                       \
    a[0]+=bflo((v).x); a[1]+=bfhi((v).x); a[2]+=bflo((v).y); a[3]+=bfhi((v).y);  \
    a[4]+=bflo((v).z); a[5]+=bfhi((v).z); a[6]+=bflo((v).w); a[7]+=bfhi((v).w);  \
  }

#pragma unroll
  for (int k = 0; k < 8; ++k) a[k] = 0.f;
  {
    uint4v v = x4[base + node * 4 + li];
    UNPK(v);
  }
  int j = 0;
  for (; j + 8 <= e; j += 8){
    int i0 = sl[j+0], i1 = sl[j+1], i2 = sl[j+2], i3 = sl[j+3];
    int i4 = sl[j+4], i5 = sl[j+5], i6 = sl[j+6], i7 = sl[j+7];
    uint4v v0 = x4[base + i0 * 4 + li];
    uint4v v1 = x4[base + i1 * 4 + li];
    uint4v v2 = x4[base + i2 * 4 + li];
    uint4v v3 = x4[base + i3 * 4 + li];
    uint4v v4 = x4[base + i4 * 4 + li];
    uint4v v5 = x4[base + i5 * 4 + li];
    uint4v v6 = x4[base + i6 * 4 + li];
    uint4v v7 = x4[base + i7 * 4 + li];
    UNPK(v0); UNPK(v1); UNPK(v2); UNPK(v3);
    UNPK(v4); UNPK(v5); UNPK(v6); UNPK(v7);
  }
  for (; j + 4 <= e; j += 4){
    int i0 = sl[j+0], i1 = sl[j+1], i2 = sl[j+2], i3 = sl[j+3];
    uint4v v0 = x4[base + i0 * 4 + li];
    uint4v v1 = x4[base + i1 * 4 + li];
    uint4v v2 = x4[base + i2 * 4 + li];
    uint4v v3 = x4[base + i3 * 4 + li];
    UNPK(v0); UNPK(v1); UNPK(v2); UNPK(v3);
  }
  for (; j < e; ++j){
    uint4v v = x4[base + sl[j] * 4 + li];
    UNPK(v);
  }
#undef UNPK

  uint4v o;
  o.x = pk2(a[0], a[1]); o.y = pk2(a[2], a[3]);
  o.z = pk2(a[4], a[5]); o.w = pk2(a[6], a[7]);
  __builtin_nontemporal_store(o, (uint4v*)hs + base + node * 4 + li);
}

// ---------------- unified GEMM: Y = [relu(affine(A))] @ W^T + bias ----------------
// 512 threads, 8 waves; 4 tiles/block, 2 waves/tile (each wave = 4 of 8 col blocks).
// isl: A in sliced layout [4][N][32]. osl: Yb written sliced.
__global__ __launch_bounds__(512, 8) void gemm_kernel(const ushort* __restrict__ A,
                                                   const ushort* __restrict__ W,
                                                   const float* __restrict__ bias,
                                                   ushort* __restrict__ Yb,
                                                   float* __restrict__ Yf,
                                                   float* __restrict__ statsOut,
                                                   const float* __restrict__ statsIn,
                                                   const float* __restrict__ gA,
                                                   const float* __restrict__ gB,
                                                   const float* __restrict__ bB,
                                                   int mode, int isl, int osl){
  __shared__ uint4v w4[128 * 17];
  __shared__ float ssum[128];
  __shared__ float ssq[128];
  __shared__ float sS[128];
  __shared__ float sT[128];
  const uint4v* Wg = (const uint4v*)W;
  for (int c = threadIdx.x; c < 2048; c += 512){
    w4[(c >> 4) * 17 + (c & 15)] = Wg[c];
  }
  if (statsIn) bn_params(statsIn, gA, gB, bB, mode, sS, sT);
  if (threadIdx.x < 128){ ssum[threadIdx.x] = 0.f; ssq[threadIdx.x] = 0.f; }
  __syncthreads();

  int wave = threadIdx.x >> 6;
  int lane = threadIdx.x & 63;
  int m = lane & 15, q = lane >> 4;
  int tl   = wave >> 1;          // local tile 0..3
  int half = wave & 1;           // column half
  int tile = blockIdx.x * 4 + tl;
  bool tv = tile < NTILES;
  const uint4v* A4 = (const uint4v*)A;

  f32x4 acc[4];
#pragma unroll
  for (int i = 0; i < 4; ++i) acc[i] = (f32x4)0.f;

  int row = tile * 16 + m;
#pragma unroll
  for (int kt = 0; kt < 4; ++kt){
    short8 af = (short8)0;
    if (tv){
      int c = kt * 4 + q;
      const uint4v* ap = isl ? (A4 + ((c >> 2) * (NN * 4) + row * 4 + (c & 3)))
                             : (A4 + row * 16 + c);
      uint4v t = __builtin_nontemporal_load(ap);
      if (statsIn){
        int kc = c * 8;
        uint4v pk;
        pk.x = pk2(fmaxf(bflo(t.x)*sS[kc+0]+sT[kc+0],0.f),
                   fmaxf(bfhi(t.x)*sS[kc+1]+sT[kc+1],0.f));
        pk.y = pk2(fmaxf(bflo(t.y)*sS[kc+2]+sT[kc+2],0.f),
                   fmaxf(bfhi(t.y)*sS[kc+3]+sT[kc+3],0.f));
        pk.z = pk2(fmaxf(bflo(t.z)*sS[kc+4]+sT[kc+4],0.f),
                   fmaxf(bfhi(t.z)*sS[kc+5]+sT[kc+5],0.f));
        pk.w = pk2(fmaxf(bflo(t.w)*sS[kc+6]+sT[kc+6],0.f),
                   fmaxf(bfhi(t.w)*sS[kc+7]+sT[kc+7],0.f));
        t = pk;
      }
      af = *(short8*)&t;
    }
#pragma unroll
    for (int t4 = 0; t4 < 4; ++t4){
      int to = half * 4 + t4;
      uint4v bw = w4[(to * 16 + m) * 17 + kt * 4 + q];
      acc[t4] = __builtin_amdgcn_mfma_f32_16x16x32_bf16(af, *(short8*)&bw, acc[t4], 0, 0, 0);
    }
  }

  bool dost = (statsOut != nullptr);
#pragma unroll
  for (int t4 = 0; t4 < 4; ++t4){
    int col = (half * 4 + t4) * 16 + m;
    float bc = bias[col];
    float ls = 0.f, lq = 0.f;
    if (tv){
#pragma unroll
      for (int r = 0; r < 4; ++r){
        float v = acc[t4][r] + bc;
        int rw = tile * 16 + q * 4 + r;
        if (Yb){
          int addr = osl ? (((col >> 5) * NN + rw) * 32 + (col & 31))
                         : (rw * 128 + col);
          __builtin_nontemporal_store(__builtin_bit_cast(ushort, f2bf(v)), Yb + addr);
        } else {
          __builtin_nontemporal_store(v, Yf + rw * 128 + col);
        }
        ls += v; lq += v * v;
      }
    }
    if (dost){
      ls += __shfl_xor(ls, 16); lq += __shfl_xor(lq, 16);
      ls += __shfl_xor(ls, 32); lq += __shfl_xor(lq, 32);
      if (tv && q == 0){ atomicAdd(&ssum[col], ls); atomicAdd(&ssq[col], lq); }
    }
  }
  if (dost){
    __syncthreads();
    if (threadIdx.x < 128){
      int sb = (blockIdx.x & (SBIN - 1)) * 256;
      atomicAdd(&statsOut[sb + threadIdx.x], ssum[threadIdx.x]);
      atomicAdd(&statsOut[sb + 128 + threadIdx.x], ssq[threadIdx.x]);
    }
  }
}

extern "C" void kernel_launch(void* const* d_in, const int* in_sizes, int n_in,
                              void* d_out, int out_size, void* d_ws, size_t ws_size,
                              hipStream_t stream) {
  const float* x     = (const float*)d_in[0];
  const int*   ei    = (const int*)d_in[1];
  const float* fc1_w = (const float*)d_in[2];
  const float* fc1_b = (const float*)d_in[3];
  const float* bn1_g = (const float*)d_in[4];
  const float* bn1_b = (const float*)d_in[5];
  const float* fc2_w = (const float*)d_in[6];
  const float* fc2_b = (const float*)d_in[7];
  const float* bn2_g = (const float*)d_in[8];
  const float* bn3_g = (const float*)d_in[10];
  const float* bn3_b = (const float*)d_in[11];
  const float* fc_w  = (const float*)d_in[12];
  const float* fc_b  = (const float*)d_in[13];

  int E = in_sizes[1] / 2;
  const int* srcp = ei;
  const int* dstp = ei + E;

  char* ws = (char*)d_ws;
  int*    cnt    = (int*)(ws + 0);           // N ints (degree)
  float*  stats  = (float*)(ws + 200064);    // 8 slices x 64 bins x 256 floats = 512KB
  int*    pos    = (int*)(ws + 724352);      // E ints
  int*    slots  = (int*)(ws + 3924352);     // N*MAXDEG ints = 12.8 MB
  ushort* wb     = (ushort*)(ws + 16724352); // 147456 bf16
  ushort* xs     = (ushort*)(ws + 17019264); // sliced x [4][N][32] bf16
  ushort* hs     = (ushort*)(ws + 29819264); // sliced h [4][N][32] bf16
  ushort* y1b    = (ushort*)(ws + 42619264); // row-major [N][128] bf16
  ushort* y2s    = (ushort*)(ws + 55419264); // sliced y2 [4][N][32] bf16

  // cnt + stats are contiguous: one memset
  hipMemsetAsync(ws, 0, 724352, stream);

  cast_all<<<2048, 256, 0, stream>>>(x, fc1_w, fc2_w, fc_w, xs, wb);

  const int EB4 = (E / 4 + 255) / 256 + 1;
  fill1_kernel<<<EB4, 256, 0, stream>>>(dstp, cnt, pos, E);
  fill2_kernel<<<EB4, 256, 0, stream>>>(srcp, dstp, pos, slots, E);

  const int gaggs = ((NN + 63) / 64) * 4;  // 782 node-blocks x 4 slices
  const int gb = (NTILES + 3) / 4;         // 782 blocks, 4 tiles each

  for (int i = 0; i < NL; ++i){
    // sliced agg: gather (+bn23 affine for i>0) -> hs
    if (i == 0){
      aggs_t<false><<<gaggs, 256, 0, stream>>>(xs, cnt, slots,
                                               nullptr, nullptr, nullptr, nullptr, hs);
    } else {
      aggs_t<true><<<gaggs, 256, 0, stream>>>(y2s, cnt, slots,
                                              stats + ((i - 1) * 2 + 1) * 16384,
                                              bn2_g + (i - 1) * 128,
                                              bn3_g + (i - 1) * 128,
                                              bn3_b + (i - 1) * 128, hs);
    }
    // fc1: hs (sliced) -> y1b (row-major), stats1
    gemm_kernel<<<gb, 512, 0, stream>>>(hs, wb + i * 16384, fc1_b + i * 128,
                                        y1b, nullptr, stats + (i * 2) * 16384,
                                        nullptr, nullptr, nullptr, nullptr, 0, 1, 0);
    // fc2: relu(bn1(y1b)) -> y2s (sliced), stats2; bn1 params inline from stats1
    gemm_kernel<<<gb, 512, 0, stream>>>(y1b, wb + 65536 + i * 16384, fc2_b + i * 128,
                                        y2s, nullptr, stats + (i * 2 + 1) * 16384,
                                        stats + (i * 2) * 16384, bn1_g + i * 128,
                                        bn1_b + i * 128, nullptr, 0, 0, 1);
  }

  // classifier: relu(bn3(bn2(y2s)))@fc_w^T + fc_b -> f32 out; bn23 params inline
  gemm_kernel<<<gb, 512, 0, stream>>>(y2s, wb + 131072, fc_b,
                                      nullptr, (float*)d_out, nullptr,
                                      stats + 7 * 16384, bn2_g + 384,
                                      bn3_g + 384, bn3_b + 384, 1, 1, 0);
}

// Round 8
// 475.295 us; speedup vs baseline: 1.0776x; 1.0776x over previous
//
#include <hip/hip_runtime.h>

#define NN 50000
#define HD 128
#define NL 4
#define BN_EPS 1e-5f
#define NTILES 3125
#define MAXDEG 64

typedef __attribute__((ext_vector_type(8))) short short8;
typedef __attribute__((ext_vector_type(4))) float f32x4;
typedef __attribute__((ext_vector_type(4))) uint uint4v;

__device__ inline ushort f2bf(float f){
  uint u = __float_as_uint(f);
  uint r = (u + 0x7fffu + ((u >> 16) & 1u)) >> 16;
  return (ushort)r;
}
__device__ inline float bflo(uint u){ return __uint_as_float(u << 16); }
__device__ inline float bfhi(uint u){ return __uint_as_float(u & 0xffff0000u); }
__device__ inline uint pk2(float lo, float hi){
  return (uint)f2bf(lo) | ((uint)f2bf(hi) << 16);
}

// ---------------- fused cast fp32 -> bf16 : x then all weights ----------------
__global__ __launch_bounds__(256) void cast_all(const float* __restrict__ x,
                                                const float* __restrict__ w1,
                                                const float* __restrict__ w2,
                                                const float* __restrict__ wf,
                                                ushort* __restrict__ xb,
                                                ushort* __restrict__ wb){
  const int NX = NN * HD / 4;          // 1,600,000 uint4-groups of x
  const int NT = NX + 36864;           // + weights
  int i = blockIdx.x * 256 + threadIdx.x;
  int stride = gridDim.x * 256;
  for (; i < NT; i += stride){
    const float* src; ushort* dst;
    if (i < NX){ src = x + i * 4; dst = xb + i * 4; }
    else {
      int k = i - NX;
      dst = wb + k * 4;
      if (k < 16384)      src = w1 + k * 4;
      else if (k < 32768) src = w2 + (k - 16384) * 4;
      else                src = wf + (k - 32768) * 4;
    }
    float4 v = *(const float4*)src;
    ushort4 r;
    r.x = f2bf(v.x); r.y = f2bf(v.y); r.z = f2bf(v.z); r.w = f2bf(v.w);
    *(ushort4*)dst = r;
  }
}

// ---------------- bucketed CSR build (no scan) ----------------
// fill1: independent return-atomics + coalesced pos write (round-4 proven pattern)
__global__ void fill1_kernel(const int* __restrict__ dst, int* __restrict__ cnt,
                             int* __restrict__ pos, int E){
  int e = (blockIdx.x * 256 + threadIdx.x) * 4;
  if (e + 4 <= E){
    int4 d = *(const int4*)(dst + e);
    int4 p;
    p.x = atomicAdd(&cnt[d.x], 1);
    p.y = atomicAdd(&cnt[d.y], 1);
    p.z = atomicAdd(&cnt[d.z], 1);
    p.w = atomicAdd(&cnt[d.w], 1);
    *(int4*)(pos + e) = p;
  } else {
    for (; e < E; ++e) pos[e] = atomicAdd(&cnt[dst[e]], 1);
  }
}

// fill2: atomic-free scatter into fixed-capacity per-node buckets
__global__ void fill2_kernel(const int* __restrict__ src, const int* __restrict__ dst,
                             const int* __restrict__ pos, int* __restrict__ slots, int E){
  int e = (blockIdx.x * 256 + threadIdx.x) * 4;
  if (e + 4 <= E){
    int4 d = *(const int4*)(dst + e);
    int4 p = *(const int4*)(pos + e);
    int4 s = *(const int4*)(src + e);
    slots[d.x * MAXDEG + p.x] = s.x;
    slots[d.y * MAXDEG + p.y] = s.y;
    slots[d.z * MAXDEG + p.z] = s.z;
    slots[d.w * MAXDEG + p.w] = s.w;
  } else {
    for (; e < E; ++e) slots[dst[e] * MAXDEG + pos[e]] = src[e];
  }
}

// ---------------- BN param computation (device helper, threads<128) ----------------
// stats stored as 8 sub-accumulators of 256 floats each (sum | sumsq)
__device__ inline void bn_params8(const float* __restrict__ st, const float* __restrict__ gA,
                                  const float* __restrict__ gB, const float* __restrict__ bB,
                                  int mode, float* sS, float* sT){
  int c = threadIdx.x;
  if (c < 128){
    float s0 = 0.f, s1 = 0.f;
#pragma unroll
    for (int k = 0; k < 8; ++k){
      s0 += st[k * 256 + c];
      s1 += st[k * 256 + 128 + c];
    }
    const float invN = 1.f / (float)NN;
    float mu = s0 * invN;
    float var = fmaxf(s1 * invN - mu * mu, 0.f);
    float S, T;
    if (mode == 0){
      S = gA[c] * rsqrtf(var + BN_EPS);
      T = gB[c] - mu * S;
    } else {
      float inv2 = rsqrtf(var + BN_EPS);
      float tt = gA[c] * inv2;
      float inv3 = rsqrtf(tt * tt * var + BN_EPS);
      S = tt * inv3 * gB[c];
      T = bB[c] - mu * S;
    }
    sS[c] = S; sT[c] = T;
  }
}

// ---------------- fused aggregation + fc1 GEMM ----------------
// Phase 1: each wave aggregates its 16 output rows. TWO nodes per lane-group are
//          processed concurrently (interleaved edge loops, 16 gathers in flight)
//          to double per-wave MLP — occupancy is grid-capped at ~12 waves/CU so
//          latency hiding must come from within the wave.
// Phase 2: Y = A @ W^T + bias, stats accumulated.
template<bool AFF>
__global__ __launch_bounds__(512, 4) void aggemm_t(const ushort* __restrict__ xin,
                                                   const int* __restrict__ deg,
                                                   const int* __restrict__ slots,
                                                   const ushort* __restrict__ W,
                                                   const float* __restrict__ bias,
                                                   ushort* __restrict__ Yb,
                                                   float* __restrict__ statsOut,
                                                   const float* __restrict__ statsIn,
                                                   const float* __restrict__ g2,
                                                   const float* __restrict__ g3,
                                                   const float* __restrict__ b3){
  __shared__ uint4v w4[128 * 17];
  __shared__ uint4v a4[8][16 * 17];   // per-wave 16x128 bf16 A-tile (+pad)
  __shared__ float ssum[128];
  __shared__ float ssq[128];
  __shared__ float sS[128];
  __shared__ float sT[128];

  const uint4v* Wg = (const uint4v*)W;
  for (int c = threadIdx.x; c < 2048; c += 512){
    w4[(c >> 4) * 17 + (c & 15)] = Wg[c];
  }
  if (AFF) bn_params8(statsIn, g2, g3, b3, 1, sS, sT);
  if (threadIdx.x < 128){ ssum[threadIdx.x] = 0.f; ssq[threadIdx.x] = 0.f; }
  __syncthreads();

  int wave = threadIdx.x >> 6;
  int lane = threadIdx.x & 63;
  int grp  = lane >> 4;          // which of the 4 concurrent node slots
  int col  = lane & 15;          // 16B chunk within the 256B row
  int tile = blockIdx.x * 8 + wave;
  bool tv = tile < NTILES;

  float S[8], T[8];
  if (AFF){
#pragma unroll
    for (int k = 0; k < 8; ++k){ S[k] = sS[col * 8 + k]; T[k] = sT[col * 8 + k]; }
  }

  const uint4v* x4 = (const uint4v*)xin;

#define INIT8(A, v)                                                             \
  if (AFF){                                                                     \
    A[0]=fmaxf(bflo((v).x)*S[0]+T[0],0.f); A[1]=fmaxf(bfhi((v).x)*S[1]+T[1],0.f); \
    A[2]=fmaxf(bflo((v).y)*S[2]+T[2],0.f); A[3]=fmaxf(bfhi((v).y)*S[3]+T[3],0.f); \
    A[4]=fmaxf(bflo((v).z)*S[4]+T[4],0.f); A[5]=fmaxf(bfhi((v).z)*S[5]+T[5],0.f); \
    A[6]=fmaxf(bflo((v).w)*S[6]+T[6],0.f); A[7]=fmaxf(bfhi((v).w)*S[7]+T[7],0.f); \
  } else {                                                                      \
    A[0]=bflo((v).x); A[1]=bfhi((v).x); A[2]=bflo((v).y); A[3]=bfhi((v).y);     \
    A[4]=bflo((v).z); A[5]=bfhi((v).z); A[6]=bflo((v).w); A[7]=bfhi((v).w);     \
  }

#define ACC8V(A, v)                                                             \
  if (AFF){                                                                     \
    A[0]+=fmaxf(bflo((v).x)*S[0]+T[0],0.f); A[1]+=fmaxf(bfhi((v).x)*S[1]+T[1],0.f); \
    A[2]+=fmaxf(bflo((v).y)*S[2]+T[2],0.f); A[3]+=fmaxf(bfhi((v).y)*S[3]+T[3],0.f); \
    A[4]+=fmaxf(bflo((v).z)*S[4]+T[4],0.f); A[5]+=fmaxf(bfhi((v).z)*S[5]+T[5],0.f); \
    A[6]+=fmaxf(bflo((v).w)*S[6]+T[6],0.f); A[7]+=fmaxf(bfhi((v).w)*S[7]+T[7],0.f); \
  } else {                                                                      \
    A[0]+=bflo((v).x); A[1]+=bfhi((v).x); A[2]+=bflo((v).y); A[3]+=bfhi((v).y); \
    A[4]+=bflo((v).z); A[5]+=bfhi((v).z); A[6]+=bflo((v).w); A[7]+=bfhi((v).w); \
  }

  if (tv){
#pragma unroll
    for (int ip = 0; ip < 2; ++ip){
      int nodeA = tile * 16 + ip * 8 + grp;
      int nodeB = tile * 16 + ip * 8 + 4 + grp;
      int eA = deg[nodeA], eB = deg[nodeB];
      const int* slA = slots + nodeA * MAXDEG;
      const int* slB = slots + nodeB * MAXDEG;
      float aA[8], aB[8];
      {
        uint4v vsA = x4[nodeA * 16 + col];
        uint4v vsB = x4[nodeB * 16 + col];
        INIT8(aA, vsA);
        INIT8(aB, vsB);
      }
      int jA = 0, jB = 0;
      // interleaved main loop: 16 gathers + 4 int4 index loads in flight
      while (jA + 8 <= eA && jB + 8 <= eB){
        int4 iaL = *(const int4*)(slA + jA);
        int4 iaH = *(const int4*)(slA + jA + 4);
        int4 ibL = *(const int4*)(slB + jB);
        int4 ibH = *(const int4*)(slB + jB + 4);
        uint4v vA0 = x4[iaL.x * 16 + col], vA1 = x4[iaL.y * 16 + col];
        uint4v vA2 = x4[iaL.z * 16 + col], vA3 = x4[iaL.w * 16 + col];
        uint4v vA4 = x4[iaH.x * 16 + col], vA5 = x4[iaH.y * 16 + col];
        uint4v vA6 = x4[iaH.z * 16 + col], vA7 = x4[iaH.w * 16 + col];
        uint4v vB0 = x4[ibL.x * 16 + col], vB1 = x4[ibL.y * 16 + col];
        uint4v vB2 = x4[ibL.z * 16 + col], vB3 = x4[ibL.w * 16 + col];
        uint4v vB4 = x4[ibH.x * 16 + col], vB5 = x4[ibH.y * 16 + col];
        uint4v vB6 = x4[ibH.z * 16 + col], vB7 = x4[ibH.w * 16 + col];
        ACC8V(aA, vA0); ACC8V(aA, vA1); ACC8V(aA, vA2); ACC8V(aA, vA3);
        ACC8V(aA, vA4); ACC8V(aA, vA5); ACC8V(aA, vA6); ACC8V(aA, vA7);
        ACC8V(aB, vB0); ACC8V(aB, vB1); ACC8V(aB, vB2); ACC8V(aB, vB3);
        ACC8V(aB, vB4); ACC8V(aB, vB5); ACC8V(aB, vB6); ACC8V(aB, vB7);
        jA += 8; jB += 8;
      }
      // drain A
      for (; jA + 8 <= eA; jA += 8){
        int4 iL = *(const int4*)(slA + jA);
        int4 iH = *(const int4*)(slA + jA + 4);
        uint4v v0 = x4[iL.x * 16 + col], v1 = x4[iL.y * 16 + col];
        uint4v v2 = x4[iL.z * 16 + col], v3 = x4[iL.w * 16 + col];
        uint4v v4 = x4[iH.x * 16 + col], v5 = x4[iH.y * 16 + col];
        uint4v v6 = x4[iH.z * 16 + col], v7 = x4[iH.w * 16 + col];
        ACC8V(aA, v0); ACC8V(aA, v1); ACC8V(aA, v2); ACC8V(aA, v3);
        ACC8V(aA, v4); ACC8V(aA, v5); ACC8V(aA, v6); ACC8V(aA, v7);
      }
      for (; jA + 4 <= eA; jA += 4){
        int4 iL = *(const int4*)(slA + jA);
        uint4v v0 = x4[iL.x * 16 + col], v1 = x4[iL.y * 16 + col];
        uint4v v2 = x4[iL.z * 16 + col], v3 = x4[iL.w * 16 + col];
        ACC8V(aA, v0); ACC8V(aA, v1); ACC8V(aA, v2); ACC8V(aA, v3);
      }
      for (; jA < eA; ++jA){
        uint4v v = x4[slA[jA] * 16 + col];
        ACC8V(aA, v);
      }
      // drain B
      for (; jB + 8 <= eB; jB += 8){
        int4 iL = *(const int4*)(slB + jB);
        int4 iH = *(const int4*)(slB + jB + 4);
        uint4v v0 = x4[iL.x * 16 + col], v1 = x4[iL.y * 16 + col];
        uint4v v2 = x4[iL.z * 16 + col], v3 = x4[iL.w * 16 + col];
        uint4v v4 = x4[iH.x * 16 + col], v5 = x4[iH.y * 16 + col];
        uint4v v6 = x4[iH.z * 16 + col], v7 = x4[iH.w * 16 + col];
        ACC8V(aB, v0); ACC8V(aB, v1); ACC8V(aB, v2); ACC8V(aB, v3);
        ACC8V(aB, v4); ACC8V(aB, v5); ACC8V(aB, v6); ACC8V(aB, v7);
      }
      for (; jB + 4 <= eB; jB += 4){
        int4 iL = *(const int4*)(slB + jB);
        uint4v v0 = x4[iL.x * 16 + col], v1 = x4[iL.y * 16 + col];
        uint4v v2 = x4[iL.z * 16 + col], v3 = x4[iL.w * 16 + col];
        ACC8V(aB, v0); ACC8V(aB, v1); ACC8V(aB, v2); ACC8V(aB, v3);
      }
      for (; jB < eB; ++jB){
        uint4v v = x4[slB[jB] * 16 + col];
        ACC8V(aB, v);
      }
      uint4v oA, oB;
      oA.x = pk2(aA[0], aA[1]); oA.y = pk2(aA[2], aA[3]);
      oA.z = pk2(aA[4], aA[5]); oA.w = pk2(aA[6], aA[7]);
      oB.x = pk2(aB[0], aB[1]); oB.y = pk2(aB[2], aB[3]);
      oB.z = pk2(aB[4], aB[5]); oB.w = pk2(aB[6], aB[7]);
      a4[wave][(ip * 8 + grp) * 17 + col] = oA;
      a4[wave][(ip * 8 + 4 + grp) * 17 + col] = oB;
    }
  }
#undef INIT8
#undef ACC8V
  __syncthreads();

  // ---- phase 2: MFMA from the wave-private LDS A-tile ----
  int m = lane & 15, q = lane >> 4;
  f32x4 acc[8];
#pragma unroll
  for (int i = 0; i < 8; ++i) acc[i] = (f32x4)0.f;

#pragma unroll
  for (int kt = 0; kt < 4; ++kt){
    uint4v t = a4[wave][m * 17 + kt * 4 + q];
    short8 af = *(short8*)&t;
#pragma unroll
    for (int to = 0; to < 8; ++to){
      uint4v bw = w4[(to * 16 + m) * 17 + kt * 4 + q];
      acc[to] = __builtin_amdgcn_mfma_f32_16x16x32_bf16(af, *(short8*)&bw, acc[to], 0, 0, 0);
    }
  }

#pragma unroll
  for (int to = 0; to < 8; ++to){
    int colo = to * 16 + m;
    float bc = bias[colo];
    float ls = 0.f, lq = 0.f;
    if (tv){
#pragma unroll
      for (int r = 0; r < 4; ++r){
        float v = acc[to][r] + bc;
        int row = tile * 16 + q * 4 + r;
        __builtin_nontemporal_store(__builtin_bit_cast(ushort, f2bf(v)), Yb + row * 128 + colo);
        ls += v; lq += v * v;
      }
    }
    ls += __shfl_xor(ls, 16); lq += __shfl_xor(lq, 16);
    ls += __shfl_xor(ls, 32); lq += __shfl_xor(lq, 32);
    if (tv && q == 0){ atomicAdd(&ssum[colo], ls); atomicAdd(&ssq[colo], lq); }
  }
  __syncthreads();
  if (threadIdx.x < 128){
    int sb = (blockIdx.x & 7) * 256;
    atomicAdd(&statsOut[sb + threadIdx.x], ssum[threadIdx.x]);
    atomicAdd(&statsOut[sb + 128 + threadIdx.x], ssq[threadIdx.x]);
  }
}

// ---------------- unified GEMM: Y = [relu(affine(A))] @ W^T + bias ----------------
// 512 threads, 8 waves, 1 tile (16 rows) per wave; grid 391.
__global__ __launch_bounds__(512) void gemm_kernel(const ushort* __restrict__ A,
                                                   const ushort* __restrict__ W,
                                                   const float* __restrict__ bias,
                                                   ushort* __restrict__ Yb,
                                                   float* __restrict__ Yf,
                                                   float* __restrict__ statsOut,
                                                   const float* __restrict__ statsIn,
                                                   const float* __restrict__ gA,
                                                   const float* __restrict__ gB,
                                                   const float* __restrict__ bB,
                                                   int mode){
  __shared__ uint4v w4[128 * 17];
  __shared__ float ssum[128];
  __shared__ float ssq[128];
  __shared__ float sS[128];
  __shared__ float sT[128];
  const uint4v* Wg = (const uint4v*)W;
  for (int c = threadIdx.x; c < 2048; c += 512){
    w4[(c >> 4) * 17 + (c & 15)] = Wg[c];
  }
  if (statsIn) bn_params8(statsIn, gA, gB, bB, mode, sS, sT);
  if (threadIdx.x < 128){ ssum[threadIdx.x] = 0.f; ssq[threadIdx.x] = 0.f; }
  __syncthreads();

  int wave = threadIdx.x >> 6;
  int lane = threadIdx.x & 63;
  int m = lane & 15, q = lane >> 4;
  int tile = blockIdx.x * 8 + wave;
  bool tv = tile < NTILES;
  const uint4v* A4 = (const uint4v*)A;

  f32x4 acc[8];
#pragma unroll
  for (int i = 0; i < 8; ++i) acc[i] = (f32x4)0.f;

#pragma unroll
  for (int kt = 0; kt < 4; ++kt){
    short8 af = (short8)0;
    if (tv){
      uint4v t = __builtin_nontemporal_load(A4 + (tile * 16 + m) * 16 + kt * 4 + q);
      if (statsIn){
        int kc = kt * 32 + q * 8;
        uint4v pk;
        pk.x = pk2(fmaxf(bflo(t.x)*sS[kc+0]+sT[kc+0],0.f),
                   fmaxf(bfhi(t.x)*sS[kc+1]+sT[kc+1],0.f));
        pk.y = pk2(fmaxf(bflo(t.y)*sS[kc+2]+sT[kc+2],0.f),
                   fmaxf(bfhi(t.y)*sS[kc+3]+sT[kc+3],0.f));
        pk.z = pk2(fmaxf(bflo(t.z)*sS[kc+4]+sT[kc+4],0.f),
                   fmaxf(bfhi(t.z)*sS[kc+5]+sT[kc+5],0.f));
        pk.w = pk2(fmaxf(bflo(t.w)*sS[kc+6]+sT[kc+6],0.f),
                   fmaxf(bfhi(t.w)*sS[kc+7]+sT[kc+7],0.f));
        t = pk;
      }
      af = *(short8*)&t;
    }
#pragma unroll
    for (int to = 0; to < 8; ++to){
      uint4v bw = w4[(to * 16 + m) * 17 + kt * 4 + q];
      acc[to] = __builtin_amdgcn_mfma_f32_16x16x32_bf16(af, *(short8*)&bw, acc[to], 0, 0, 0);
    }
  }

  bool dost = (statsOut != nullptr);
#pragma unroll
  for (int to = 0; to < 8; ++to){
    int col = to * 16 + m;
    float bc = bias[col];
    float ls = 0.f, lq = 0.f;
    if (tv){
#pragma unroll
      for (int r = 0; r < 4; ++r){
        float v = acc[to][r] + bc;
        int row = tile * 16 + q * 4 + r;
        if (Yb) __builtin_nontemporal_store(__builtin_bit_cast(ushort, f2bf(v)), Yb + row * 128 + col);
        else    __builtin_nontemporal_store(v, Yf + row * 128 + col);
        ls += v; lq += v * v;
      }
    }
    if (dost){
      ls += __shfl_xor(ls, 16); lq += __shfl_xor(lq, 16);
      ls += __shfl_xor(ls, 32); lq += __shfl_xor(lq, 32);
      if (tv && q == 0){ atomicAdd(&ssum[col], ls); atomicAdd(&ssq[col], lq); }
    }
  }
  if (dost){
    __syncthreads();
    if (threadIdx.x < 128){
      int sb = (blockIdx.x & 7) * 256;
      atomicAdd(&statsOut[sb + threadIdx.x], ssum[threadIdx.x]);
      atomicAdd(&statsOut[sb + 128 + threadIdx.x], ssq[threadIdx.x]);
    }
  }
}

extern "C" void kernel_launch(void* const* d_in, const int* in_sizes, int n_in,
                              void* d_out, int out_size, void* d_ws, size_t ws_size,
                              hipStream_t stream) {
  const float* x     = (const float*)d_in[0];
  const int*   ei    = (const int*)d_in[1];
  const float* fc1_w = (const float*)d_in[2];
  const float* fc1_b = (const float*)d_in[3];
  const float* bn1_g = (const float*)d_in[4];
  const float* bn1_b = (const float*)d_in[5];
  const float* fc2_w = (const float*)d_in[6];
  const float* fc2_b = (const float*)d_in[7];
  const float* bn2_g = (const float*)d_in[8];
  const float* bn3_g = (const float*)d_in[10];
  const float* bn3_b = (const float*)d_in[11];
  const float* fc_w  = (const float*)d_in[12];
  const float* fc_b  = (const float*)d_in[13];

  int E = in_sizes[1] / 2;
  const int* srcp = ei;
  const int* dstp = ei + E;

  char* ws = (char*)d_ws;
  int*    cnt    = (int*)(ws + 0);           // N ints (degree)
  float*  stats  = (float*)(ws + 200064);    // 8 slices x 8 sub x 256 floats = 64KB
  int*    pos    = (int*)(ws + 265600);      // E ints
  int*    slots  = (int*)(ws + 3465600);     // N*MAXDEG ints = 12.8 MB
  ushort* wb     = (ushort*)(ws + 16265600); // 147456 bf16
  ushort* xb     = (ushort*)(ws + 16560512); // N*128 bf16
  ushort* y1b    = (ushort*)(ws + 29360512); // N*128 bf16
  ushort* y2b    = (ushort*)(ws + 42160512); // N*128 bf16

  // cnt + stats are contiguous: one memset
  hipMemsetAsync(ws, 0, 265600, stream);

  cast_all<<<2048, 256, 0, stream>>>(x, fc1_w, fc2_w, fc_w, xb, wb);

  const int EB4 = (E / 4 + 255) / 256 + 1;
  fill1_kernel<<<EB4, 256, 0, stream>>>(dstp, cnt, pos, E);
  fill2_kernel<<<EB4, 256, 0, stream>>>(srcp, dstp, pos, slots, E);

  const int gb = (NTILES + 7) / 8;  // 391 blocks x 8 waves

  for (int i = 0; i < NL; ++i){
    // fused agg + fc1: gather (+bn23 affine for i>0) -> LDS tile -> MFMA -> y1b, stats1
    if (i == 0){
      aggemm_t<false><<<gb, 512, 0, stream>>>(xb, cnt, slots, wb + i * 16384,
                                              fc1_b + i * 128, y1b,
                                              stats + (i * 2) * 2048,
                                              nullptr, nullptr, nullptr, nullptr);
    } else {
      aggemm_t<true><<<gb, 512, 0, stream>>>(y2b, cnt, slots, wb + i * 16384,
                                             fc1_b + i * 128, y1b,
                                             stats + (i * 2) * 2048,
                                             stats + ((i - 1) * 2 + 1) * 2048,
                                             bn2_g + (i - 1) * 128,
                                             bn3_g + (i - 1) * 128,
                                             bn3_b + (i - 1) * 128);
    }
    // fc2: relu(bn1(y1b)) -> y2b (bf16), stats2; bn1 params inline from stats1
    gemm_kernel<<<gb, 512, 0, stream>>>(y1b, wb + 65536 + i * 16384, fc2_b + i * 128,
                                        y2b, nullptr, stats + (i * 2 + 1) * 2048,
                                        stats + (i * 2) * 2048, bn1_g + i * 128,
                                        bn1_b + i * 128, nullptr, 0);
  }

  // classifier: relu(bn3(bn2(y2b)))@fc_w^T + fc_b -> f32 out; bn23 params inline
  gemm_kernel<<<gb, 512, 0, stream>>>(y2b, wb + 131072, fc_b,
                                      nullptr, (float*)d_out, nullptr,
                                      stats + 7 * 2048, bn2_g + 384,
                                      bn3_g + 384, bn3_b + 384, 1);
}

// Round 9
// 469.482 us; speedup vs baseline: 1.0909x; 1.0124x over previous
//
#include <hip/hip_runtime.h>

#define NN 50000
#define HD 128
#define NL 4
#define BN_EPS 1e-5f
#define NTILES 3125
#define MAXDEG 64

typedef __attribute__((ext_vector_type(8))) short short8;
typedef __attribute__((ext_vector_type(4))) float f32x4;
typedef __attribute__((ext_vector_type(4))) uint uint4v;

__device__ inline ushort f2bf(float f){
  uint u = __float_as_uint(f);
  uint r = (u + 0x7fffu + ((u >> 16) & 1u)) >> 16;
  return (ushort)r;
}
__device__ inline float bflo(uint u){ return __uint_as_float(u << 16); }
__device__ inline float bfhi(uint u){ return __uint_as_float(u & 0xffff0000u); }
__device__ inline uint pk2(float lo, float hi){
  return (uint)f2bf(lo) | ((uint)f2bf(hi) << 16);
}

// ---------------- fused cast fp32 -> bf16 : x then all weights ----------------
__global__ __launch_bounds__(256) void cast_all(const float* __restrict__ x,
                                                const float* __restrict__ w1,
                                                const float* __restrict__ w2,
                                                const float* __restrict__ wf,
                                                ushort* __restrict__ xb,
                                                ushort* __restrict__ wb){
  const int NX = NN * HD / 4;          // 1,600,000 uint4-groups of x
  const int NT = NX + 36864;           // + weights
  int i = blockIdx.x * 256 + threadIdx.x;
  int stride = gridDim.x * 256;
  for (; i < NT; i += stride){
    const float* src; ushort* dst;
    if (i < NX){ src = x + i * 4; dst = xb + i * 4; }
    else {
      int k = i - NX;
      dst = wb + k * 4;
      if (k < 16384)      src = w1 + k * 4;
      else if (k < 32768) src = w2 + (k - 16384) * 4;
      else                src = wf + (k - 32768) * 4;
    }
    float4 v = *(const float4*)src;
    ushort4 r;
    r.x = f2bf(v.x); r.y = f2bf(v.y); r.z = f2bf(v.z); r.w = f2bf(v.w);
    *(ushort4*)dst = r;
  }
}

// ---------------- bucketed CSR build (no scan) ----------------
// fill1: independent return-atomics + coalesced pos write (round-4 proven pattern)
__global__ void fill1_kernel(const int* __restrict__ dst, int* __restrict__ cnt,
                             int* __restrict__ pos, int E){
  int e = (blockIdx.x * 256 + threadIdx.x) * 4;
  if (e + 4 <= E){
    int4 d = *(const int4*)(dst + e);
    int4 p;
    p.x = atomicAdd(&cnt[d.x], 1);
    p.y = atomicAdd(&cnt[d.y], 1);
    p.z = atomicAdd(&cnt[d.z], 1);
    p.w = atomicAdd(&cnt[d.w], 1);
    *(int4*)(pos + e) = p;
  } else {
    for (; e < E; ++e) pos[e] = atomicAdd(&cnt[dst[e]], 1);
  }
}

// fill2: atomic-free scatter into fixed-capacity per-node buckets
__global__ void fill2_kernel(const int* __restrict__ src, const int* __restrict__ dst,
                             const int* __restrict__ pos, int* __restrict__ slots, int E){
  int e = (blockIdx.x * 256 + threadIdx.x) * 4;
  if (e + 4 <= E){
    int4 d = *(const int4*)(dst + e);
    int4 p = *(const int4*)(pos + e);
    int4 s = *(const int4*)(src + e);
    slots[d.x * MAXDEG + p.x] = s.x;
    slots[d.y * MAXDEG + p.y] = s.y;
    slots[d.z * MAXDEG + p.z] = s.z;
    slots[d.w * MAXDEG + p.w] = s.w;
  } else {
    for (; e < E; ++e) slots[dst[e] * MAXDEG + pos[e]] = src[e];
  }
}

// ---------------- BN param computation (device helper, threads<128) ----------------
// stats stored as 8 sub-accumulators of 256 floats each (sum | sumsq)
__device__ inline void bn_params8(const float* __restrict__ st, const float* __restrict__ gA,
                                  const float* __restrict__ gB, const float* __restrict__ bB,
                                  int mode, float* sS, float* sT){
  int c = threadIdx.x;
  if (c < 128){
    float s0 = 0.f, s1 = 0.f;
#pragma unroll
    for (int k = 0; k < 8; ++k){
      s0 += st[k * 256 + c];
      s1 += st[k * 256 + 128 + c];
    }
    const float invN = 1.f / (float)NN;
    float mu = s0 * invN;
    float var = fmaxf(s1 * invN - mu * mu, 0.f);
    float S, T;
    if (mode == 0){
      S = gA[c] * rsqrtf(var + BN_EPS);
      T = gB[c] - mu * S;
    } else {
      float inv2 = rsqrtf(var + BN_EPS);
      float tt = gA[c] * inv2;
      float inv3 = rsqrtf(tt * tt * var + BN_EPS);
      S = tt * inv3 * gB[c];
      T = bB[c] - mu * S;
    }
    sS[c] = S; sT[c] = T;
  }
}

// ---------------- fused aggregation + fc1 GEMM ----------------
// Phase 1: each wave aggregates its 16 output rows (4 nodes at a time, 16 lanes/row,
//          optional composed bn3(bn2(.))+relu on each gathered row) into a wave-
//          private LDS A-tile. Self rows / degrees / slot ptrs for all 4 quads are
//          hoisted so their loads overlap the first quad's gathers.
// Phase 2: Y = A @ W^T + bias, stats accumulated. Y stores are PLAIN (not
//          nontemporal): scalar nt stores bypassed L2 write-combining and caused
//          ~3x write amplification (R5: WRITE_SIZE 47MB vs ~13MB logical).
template<bool AFF>
__global__ __launch_bounds__(512, 4) void aggemm_t(const ushort* __restrict__ xin,
                                                   const int* __restrict__ deg,
                                                   const int* __restrict__ slots,
                                                   const ushort* __restrict__ W,
                                                   const float* __restrict__ bias,
                                                   ushort* __restrict__ Yb,
                                                   float* __restrict__ statsOut,
                                                   const float* __restrict__ statsIn,
                                                   const float* __restrict__ g2,
                                                   const float* __restrict__ g3,
                                                   const float* __restrict__ b3){
  __shared__ uint4v w4[128 * 17];
  __shared__ uint4v a4[8][16 * 17];   // per-wave 16x128 bf16 A-tile (+pad)
  __shared__ float ssum[128];
  __shared__ float ssq[128];
  __shared__ float sS[128];
  __shared__ float sT[128];

  const uint4v* Wg = (const uint4v*)W;
  for (int c = threadIdx.x; c < 2048; c += 512){
    w4[(c >> 4) * 17 + (c & 15)] = Wg[c];
  }
  if (AFF) bn_params8(statsIn, g2, g3, b3, 1, sS, sT);
  if (threadIdx.x < 128){ ssum[threadIdx.x] = 0.f; ssq[threadIdx.x] = 0.f; }
  __syncthreads();

  int wave = threadIdx.x >> 6;
  int lane = threadIdx.x & 63;
  int grp  = lane >> 4;          // which of the wave's 4 concurrent nodes
  int col  = lane & 15;          // 16B chunk within the 256B row
  int tile = blockIdx.x * 8 + wave;
  bool tv = tile < NTILES;

  float S[8], T[8];
  if (AFF){
#pragma unroll
    for (int k = 0; k < 8; ++k){ S[k] = sS[col * 8 + k]; T[k] = sT[col * 8 + k]; }
  }

  const uint4v* x4 = (const uint4v*)xin;

#define INIT8(A, v)                                                             \
  if (AFF){                                                                     \
    A[0]=fmaxf(bflo((v).x)*S[0]+T[0],0.f); A[1]=fmaxf(bfhi((v).x)*S[1]+T[1],0.f); \
    A[2]=fmaxf(bflo((v).y)*S[2]+T[2],0.f); A[3]=fmaxf(bfhi((v).y)*S[3]+T[3],0.f); \
    A[4]=fmaxf(bflo((v).z)*S[4]+T[4],0.f); A[5]=fmaxf(bfhi((v).z)*S[5]+T[5],0.f); \
    A[6]=fmaxf(bflo((v).w)*S[6]+T[6],0.f); A[7]=fmaxf(bfhi((v).w)*S[7]+T[7],0.f); \
  } else {                                                                      \
    A[0]=bflo((v).x); A[1]=bfhi((v).x); A[2]=bflo((v).y); A[3]=bfhi((v).y);     \
    A[4]=bflo((v).z); A[5]=bfhi((v).z); A[6]=bflo((v).w); A[7]=bfhi((v).w);     \
  }

#define ACC8(v)                                                                 \
  if (AFF){                                                                     \
    a[0]+=fmaxf(bflo((v).x)*S[0]+T[0],0.f); a[1]+=fmaxf(bfhi((v).x)*S[1]+T[1],0.f); \
    a[2]+=fmaxf(bflo((v).y)*S[2]+T[2],0.f); a[3]+=fmaxf(bfhi((v).y)*S[3]+T[3],0.f); \
    a[4]+=fmaxf(bflo((v).z)*S[4]+T[4],0.f); a[5]+=fmaxf(bfhi((v).z)*S[5]+T[5],0.f); \
    a[6]+=fmaxf(bflo((v).w)*S[6]+T[6],0.f); a[7]+=fmaxf(bfhi((v).w)*S[7]+T[7],0.f); \
  } else {                                                                      \
    a[0]+=bflo((v).x); a[1]+=bfhi((v).x); a[2]+=bflo((v).y); a[3]+=bfhi((v).y); \
    a[4]+=bflo((v).z); a[5]+=bfhi((v).z); a[6]+=bflo((v).w); a[7]+=bfhi((v).w); \
  }

  if (tv){
    // hoisted startup loads for all 4 node-quads (static arrays, fully unrolled)
    int eAr[4];
    const int* slAr[4];
    uint4v selfr[4];
#pragma unroll
    for (int it = 0; it < 4; ++it){
      int node = tile * 16 + it * 4 + grp;
      eAr[it] = deg[node];
      slAr[it] = slots + node * MAXDEG;
      selfr[it] = x4[node * 16 + col];
    }
#pragma unroll
    for (int it = 0; it < 4; ++it){
      int e = eAr[it];
      const int* sl = slAr[it];
      float a[8];
      INIT8(a, selfr[it]);
      int j = 0;
      for (; j + 8 <= e; j += 8){
        int i0 = sl[j+0], i1 = sl[j+1], i2 = sl[j+2], i3 = sl[j+3];
        int i4 = sl[j+4], i5 = sl[j+5], i6 = sl[j+6], i7 = sl[j+7];
        uint4v v0 = x4[i0 * 16 + col];
        uint4v v1 = x4[i1 * 16 + col];
        uint4v v2 = x4[i2 * 16 + col];
        uint4v v3 = x4[i3 * 16 + col];
        uint4v v4 = x4[i4 * 16 + col];
        uint4v v5 = x4[i5 * 16 + col];
        uint4v v6 = x4[i6 * 16 + col];
        uint4v v7 = x4[i7 * 16 + col];
        ACC8(v0); ACC8(v1); ACC8(v2); ACC8(v3);
        ACC8(v4); ACC8(v5); ACC8(v6); ACC8(v7);
      }
      for (; j + 4 <= e; j += 4){
        int i0 = sl[j+0], i1 = sl[j+1], i2 = sl[j+2], i3 = sl[j+3];
        uint4v v0 = x4[i0 * 16 + col];
        uint4v v1 = x4[i1 * 16 + col];
        uint4v v2 = x4[i2 * 16 + col];
        uint4v v3 = x4[i3 * 16 + col];
        ACC8(v0); ACC8(v1); ACC8(v2); ACC8(v3);
      }
      for (; j < e; ++j){
        uint4v v = x4[sl[j] * 16 + col];
        ACC8(v);
      }
      uint4v o;
      o.x = pk2(a[0], a[1]); o.y = pk2(a[2], a[3]);
      o.z = pk2(a[4], a[5]); o.w = pk2(a[6], a[7]);
      a4[wave][(it * 4 + grp) * 17 + col] = o;
    }
  }
#undef INIT8
#undef ACC8
  __syncthreads();

  // ---- phase 2: MFMA from the wave-private LDS A-tile ----
  int m = lane & 15, q = lane >> 4;
  f32x4 acc[8];
#pragma unroll
  for (int i = 0; i < 8; ++i) acc[i] = (f32x4)0.f;

#pragma unroll
  for (int kt = 0; kt < 4; ++kt){
    uint4v t = a4[wave][m * 17 + kt * 4 + q];
    short8 af = *(short8*)&t;
#pragma unroll
    for (int to = 0; to < 8; ++to){
      uint4v bw = w4[(to * 16 + m) * 17 + kt * 4 + q];
      acc[to] = __builtin_amdgcn_mfma_f32_16x16x32_bf16(af, *(short8*)&bw, acc[to], 0, 0, 0);
    }
  }

#pragma unroll
  for (int to = 0; to < 8; ++to){
    int colo = to * 16 + m;
    float bc = bias[colo];
    float ls = 0.f, lq = 0.f;
    if (tv){
#pragma unroll
      for (int r = 0; r < 4; ++r){
        float v = acc[to][r] + bc;
        int row = tile * 16 + q * 4 + r;
        Yb[row * 128 + colo] = __builtin_bit_cast(ushort, f2bf(v));
        ls += v; lq += v * v;
      }
    }
    ls += __shfl_xor(ls, 16); lq += __shfl_xor(lq, 16);
    ls += __shfl_xor(ls, 32); lq += __shfl_xor(lq, 32);
    if (tv && q == 0){ atomicAdd(&ssum[colo], ls); atomicAdd(&ssq[colo], lq); }
  }
  __syncthreads();
  if (threadIdx.x < 128){
    int sb = (blockIdx.x & 7) * 256;
    atomicAdd(&statsOut[sb + threadIdx.x], ssum[threadIdx.x]);
    atomicAdd(&statsOut[sb + 128 + threadIdx.x], ssq[threadIdx.x]);
  }
}

// ---------------- unified GEMM: Y = [relu(affine(A))] @ W^T + bias ----------------
// 512 threads, 8 waves, 1 tile (16 rows) per wave; grid 391.
__global__ __launch_bounds__(512) void gemm_kernel(const ushort* __restrict__ A,
                                                   const ushort* __restrict__ W,
                                                   const float* __restrict__ bias,
                                                   ushort* __restrict__ Yb,
                                                   float* __restrict__ Yf,
                                                   float* __restrict__ statsOut,
                                                   const float* __restrict__ statsIn,
                                                   const float* __restrict__ gA,
                                                   const float* __restrict__ gB,
                                                   const float* __restrict__ bB,
                                                   int mode){
  __shared__ uint4v w4[128 * 17];
  __shared__ float ssum[128];
  __shared__ float ssq[128];
  __shared__ float sS[128];
  __shared__ float sT[128];
  const uint4v* Wg = (const uint4v*)W;
  for (int c = threadIdx.x; c < 2048; c += 512){
    w4[(c >> 4) * 17 + (c & 15)] = Wg[c];
  }
  if (statsIn) bn_params8(statsIn, gA, gB, bB, mode, sS, sT);
  if (threadIdx.x < 128){ ssum[threadIdx.x] = 0.f; ssq[threadIdx.x] = 0.f; }
  __syncthreads();

  int wave = threadIdx.x >> 6;
  int lane = threadIdx.x & 63;
  int m = lane & 15, q = lane >> 4;
  int tile = blockIdx.x * 8 + wave;
  bool tv = tile < NTILES;
  const uint4v* A4 = (const uint4v*)A;

  f32x4 acc[8];
#pragma unroll
  for (int i = 0; i < 8; ++i) acc[i] = (f32x4)0.f;

#pragma unroll
  for (int kt = 0; kt < 4; ++kt){
    short8 af = (short8)0;
    if (tv){
      uint4v t = __builtin_nontemporal_load(A4 + (tile * 16 + m) * 16 + kt * 4 + q);
      if (statsIn){
        int kc = kt * 32 + q * 8;
        uint4v pk;
        pk.x = pk2(fmaxf(bflo(t.x)*sS[kc+0]+sT[kc+0],0.f),
                   fmaxf(bfhi(t.x)*sS[kc+1]+sT[kc+1],0.f));
        pk.y = pk2(fmaxf(bflo(t.y)*sS[kc+2]+sT[kc+2],0.f),
                   fmaxf(bfhi(t.y)*sS[kc+3]+sT[kc+3],0.f));
        pk.z = pk2(fmaxf(bflo(t.z)*sS[kc+4]+sT[kc+4],0.f),
                   fmaxf(bfhi(t.z)*sS[kc+5]+sT[kc+5],0.f));
        pk.w = pk2(fmaxf(bflo(t.w)*sS[kc+6]+sT[kc+6],0.f),
                   fmaxf(bfhi(t.w)*sS[kc+7]+sT[kc+7],0.f));
        t = pk;
      }
      af = *(short8*)&t;
    }
#pragma unroll
    for (int to = 0; to < 8; ++to){
      uint4v bw = w4[(to * 16 + m) * 17 + kt * 4 + q];
      acc[to] = __builtin_amdgcn_mfma_f32_16x16x32_bf16(af, *(short8*)&bw, acc[to], 0, 0, 0);
    }
  }

  bool dost = (statsOut != nullptr);
#pragma unroll
  for (int to = 0; to < 8; ++to){
    int col = to * 16 + m;
    float bc = bias[col];
    float ls = 0.f, lq = 0.f;
    if (tv){
#pragma unroll
      for (int r = 0; r < 4; ++r){
        float v = acc[to][r] + bc;
        int row = tile * 16 + q * 4 + r;
        if (Yb) Yb[row * 128 + col] = __builtin_bit_cast(ushort, f2bf(v));
        else    Yf[row * 128 + col] = v;
        ls += v; lq += v * v;
      }
    }
    if (dost){
      ls += __shfl_xor(ls, 16); lq += __shfl_xor(lq, 16);
      ls += __shfl_xor(ls, 32); lq += __shfl_xor(lq, 32);
      if (tv && q == 0){ atomicAdd(&ssum[col], ls); atomicAdd(&ssq[col], lq); }
    }
  }
  if (dost){
    __syncthreads();
    if (threadIdx.x < 128){
      int sb = (blockIdx.x & 7) * 256;
      atomicAdd(&statsOut[sb + threadIdx.x], ssum[threadIdx.x]);
      atomicAdd(&statsOut[sb + 128 + threadIdx.x], ssq[threadIdx.x]);
    }
  }
}

extern "C" void kernel_launch(void* const* d_in, const int* in_sizes, int n_in,
                              void* d_out, int out_size, void* d_ws, size_t ws_size,
                              hipStream_t stream) {
  const float* x     = (const float*)d_in[0];
  const int*   ei    = (const int*)d_in[1];
  const float* fc1_w = (const float*)d_in[2];
  const float* fc1_b = (const float*)d_in[3];
  const float* bn1_g = (const float*)d_in[4];
  const float* bn1_b = (const float*)d_in[5];
  const float* fc2_w = (const float*)d_in[6];
  const float* fc2_b = (const float*)d_in[7];
  const float* bn2_g = (const float*)d_in[8];
  const float* bn3_g = (const float*)d_in[10];
  const float* bn3_b = (const float*)d_in[11];
  const float* fc_w  = (const float*)d_in[12];
  const float* fc_b  = (const float*)d_in[13];

  int E = in_sizes[1] / 2;
  const int* srcp = ei;
  const int* dstp = ei + E;

  char* ws = (char*)d_ws;
  int*    cnt    = (int*)(ws + 0);           // N ints (degree)
  float*  stats  = (float*)(ws + 200064);    // 8 slices x 8 sub x 256 floats = 64KB
  int*    pos    = (int*)(ws + 265600);      // E ints
  int*    slots  = (int*)(ws + 3465600);     // N*MAXDEG ints = 12.8 MB
  ushort* wb     = (ushort*)(ws + 16265600); // 147456 bf16
  ushort* xb     = (ushort*)(ws + 16560512); // N*128 bf16
  ushort* y1b    = (ushort*)(ws + 29360512); // N*128 bf16
  ushort* y2b    = (ushort*)(ws + 42160512); // N*128 bf16

  // cnt + stats are contiguous: one memset
  hipMemsetAsync(ws, 0, 265600, stream);

  cast_all<<<2048, 256, 0, stream>>>(x, fc1_w, fc2_w, fc_w, xb, wb);

  const int EB4 = (E / 4 + 255) / 256 + 1;
  fill1_kernel<<<EB4, 256, 0, stream>>>(dstp, cnt, pos, E);
  fill2_kernel<<<EB4, 256, 0, stream>>>(srcp, dstp, pos, slots, E);

  const int gb = (NTILES + 7) / 8;  // 391 blocks x 8 waves

  for (int i = 0; i < NL; ++i){
    // fused agg + fc1: gather (+bn23 affine for i>0) -> LDS tile -> MFMA -> y1b, stats1
    if (i == 0){
      aggemm_t<false><<<gb, 512, 0, stream>>>(xb, cnt, slots, wb + i * 16384,
                                              fc1_b + i * 128, y1b,
                                              stats + (i * 2) * 2048,
                                              nullptr, nullptr, nullptr, nullptr);
    } else {
      aggemm_t<true><<<gb, 512, 0, stream>>>(y2b, cnt, slots, wb + i * 16384,
                                             fc1_b + i * 128, y1b,
                                             stats + (i * 2) * 2048,
                                             stats + ((i - 1) * 2 + 1) * 2048,
                                             bn2_g + (i - 1) * 128,
                                             bn3_g + (i - 1) * 128,
                                             bn3_b + (i - 1) * 128);
    }
    // fc2: relu(bn1(y1b)) -> y2b (bf16), stats2; bn1 params inline from stats1
    gemm_kernel<<<gb, 512, 0, stream>>>(y1b, wb + 65536 + i * 16384, fc2_b + i * 128,
                                        y2b, nullptr, stats + (i * 2 + 1) * 2048,
                                        stats + (i * 2) * 2048, bn1_g + i * 128,
                                        bn1_b + i * 128, nullptr, 0);
  }

  // classifier: relu(bn3(bn2(y2b)))@fc_w^T + fc_b -> f32 out; bn23 params inline
  gemm_kernel<<<gb, 512, 0, stream>>>(y2b, wb + 131072, fc_b,
                                      nullptr, (float*)d_out, nullptr,
                                      stats + 7 * 2048, bn2_g + 384,
                                      bn3_g + 384, bn3_b + 384, 1);
}

// Round 10
// 463.803 us; speedup vs baseline: 1.1043x; 1.0122x over previous
//
#include <hip/hip_runtime.h>

#define NN 50000
#define HD 128
#define NL 4
#define BN_EPS 1e-5f
#define NTILES 3125
#define MAXDEG 64

typedef __attribute__((ext_vector_type(8))) short short8;
typedef __attribute__((ext_vector_type(4))) float f32x4;
typedef __attribute__((ext_vector_type(4))) uint uint4v;

__device__ inline ushort f2bf(float f){
  uint u = __float_as_uint(f);
  uint r = (u + 0x7fffu + ((u >> 16) & 1u)) >> 16;
  return (ushort)r;
}
__device__ inline float bflo(uint u){ return __uint_as_float(u << 16); }
__device__ inline float bfhi(uint u){ return __uint_as_float(u & 0xffff0000u); }
__device__ inline uint pk2(float lo, float hi){
  return (uint)f2bf(lo) | ((uint)f2bf(hi) << 16);
}

// ---------------- fused cast fp32 -> bf16 (+ workspace zero-fill) ----------------
// Also zeroes cnt+stats (first ZB4 uint4 of workspace) - removes a memset dispatch.
__global__ __launch_bounds__(256) void cast_all(const float* __restrict__ x,
                                                const float* __restrict__ w1,
                                                const float* __restrict__ w2,
                                                const float* __restrict__ wf,
                                                ushort* __restrict__ xb,
                                                ushort* __restrict__ wb,
                                                uint* __restrict__ zptr){
  const int ZB4 = 16600;               // 265600 B of cnt+stats as uint4
  {
    int z = blockIdx.x * 256 + threadIdx.x;
    int zstride = gridDim.x * 256;
    uint4v zero = (uint4v)0u;
    for (; z < ZB4; z += zstride) ((uint4v*)zptr)[z] = zero;
  }
  const int NX = NN * HD / 4;          // 1,600,000 uint4-groups of x
  const int NT = NX + 36864;           // + weights
  int i = blockIdx.x * 256 + threadIdx.x;
  int stride = gridDim.x * 256;
  for (; i < NT; i += stride){
    const float* src; ushort* dst;
    if (i < NX){ src = x + i * 4; dst = xb + i * 4; }
    else {
      int k = i - NX;
      dst = wb + k * 4;
      if (k < 16384)      src = w1 + k * 4;
      else if (k < 32768) src = w2 + (k - 16384) * 4;
      else                src = wf + (k - 32768) * 4;
    }
    float4 v = *(const float4*)src;
    ushort4 r;
    r.x = f2bf(v.x); r.y = f2bf(v.y); r.z = f2bf(v.z); r.w = f2bf(v.w);
    *(ushort4*)dst = r;
  }
}

// ---------------- bucketed CSR build (no scan) ----------------
// fill1: independent return-atomics + coalesced pos write (round-4 proven pattern)
__global__ void fill1_kernel(const int* __restrict__ dst, int* __restrict__ cnt,
                             int* __restrict__ pos, int E){
  int e = (blockIdx.x * 256 + threadIdx.x) * 4;
  if (e + 4 <= E){
    int4 d = *(const int4*)(dst + e);
    int4 p;
    p.x = atomicAdd(&cnt[d.x], 1);
    p.y = atomicAdd(&cnt[d.y], 1);
    p.z = atomicAdd(&cnt[d.z], 1);
    p.w = atomicAdd(&cnt[d.w], 1);
    *(int4*)(pos + e) = p;
  } else {
    for (; e < E; ++e) pos[e] = atomicAdd(&cnt[dst[e]], 1);
  }
}

// fill2: atomic-free scatter into fixed-capacity per-node buckets
__global__ void fill2_kernel(const int* __restrict__ src, const int* __restrict__ dst,
                             const int* __restrict__ pos, int* __restrict__ slots, int E){
  int e = (blockIdx.x * 256 + threadIdx.x) * 4;
  if (e + 4 <= E){
    int4 d = *(const int4*)(dst + e);
    int4 p = *(const int4*)(pos + e);
    int4 s = *(const int4*)(src + e);
    slots[d.x * MAXDEG + p.x] = s.x;
    slots[d.y * MAXDEG + p.y] = s.y;
    slots[d.z * MAXDEG + p.z] = s.z;
    slots[d.w * MAXDEG + p.w] = s.w;
  } else {
    for (; e < E; ++e) slots[dst[e] * MAXDEG + pos[e]] = src[e];
  }
}

// ---------------- BN param computation (device helper, threads<128) ----------------
// stats stored as 8 sub-accumulators of 256 floats each (sum | sumsq)
__device__ inline void bn_params8(const float* __restrict__ st, const float* __restrict__ gA,
                                  const float* __restrict__ gB, const float* __restrict__ bB,
                                  int mode, float* sS, float* sT){
  int c = threadIdx.x;
  if (c < 128){
    float s0 = 0.f, s1 = 0.f;
#pragma unroll
    for (int k = 0; k < 8; ++k){
      s0 += st[k * 256 + c];
      s1 += st[k * 256 + 128 + c];
    }
    const float invN = 1.f / (float)NN;
    float mu = s0 * invN;
    float var = fmaxf(s1 * invN - mu * mu, 0.f);
    float S, T;
    if (mode == 0){
      S = gA[c] * rsqrtf(var + BN_EPS);
      T = gB[c] - mu * S;
    } else {
      float inv2 = rsqrtf(var + BN_EPS);
      float tt = gA[c] * inv2;
      float inv3 = rsqrtf(tt * tt * var + BN_EPS);
      S = tt * inv3 * gB[c];
      T = bB[c] - mu * S;
    }
    sS[c] = S; sT[c] = T;
  }
}

// ---------------- fused aggregation + fc1 GEMM (R5 structure) ----------------
// Phase 1: each wave aggregates its 16 output rows (4 nodes at a time, 16 lanes/row,
//          optional composed bn3(bn2(.))+relu on each gathered row) into a wave-
//          private LDS A-tile.
// Phase 2: Y = A @ W^T + bias, stats accumulated.
// launch_bounds (512,2): VGPR budget ~256 so the AFF variant's live set (~80 regs)
// does not spill at the old 64-reg allocation (R5's unexplained 28MB WRITE excess).
// LDS (71.7KB -> 2 blocks/CU) remains the occupancy limiter either way.
template<bool AFF>
__global__ __launch_bounds__(512, 2) void aggemm_t(const ushort* __restrict__ xin,
                                                   const int* __restrict__ deg,
                                                   const int* __restrict__ slots,
                                                   const ushort* __restrict__ W,
                                                   const float* __restrict__ bias,
                                                   ushort* __restrict__ Yb,
                                                   float* __restrict__ statsOut,
                                                   const float* __restrict__ statsIn,
                                                   const float* __restrict__ g2,
                                                   const float* __restrict__ g3,
                                                   const float* __restrict__ b3){
  __shared__ uint4v w4[128 * 17];
  __shared__ uint4v a4[8][16 * 17];   // per-wave 16x128 bf16 A-tile (+pad)
  __shared__ float ssum[128];
  __shared__ float ssq[128];
  __shared__ float sS[128];
  __shared__ float sT[128];

  const uint4v* Wg = (const uint4v*)W;
  for (int c = threadIdx.x; c < 2048; c += 512){
    w4[(c >> 4) * 17 + (c & 15)] = Wg[c];
  }
  if (AFF) bn_params8(statsIn, g2, g3, b3, 1, sS, sT);
  if (threadIdx.x < 128){ ssum[threadIdx.x] = 0.f; ssq[threadIdx.x] = 0.f; }
  __syncthreads();

  int wave = threadIdx.x >> 6;
  int lane = threadIdx.x & 63;
  int grp  = lane >> 4;          // which of the 4 concurrent node slots
  int col  = lane & 15;          // 16B chunk within the 256B row
  int tile = blockIdx.x * 8 + wave;
  bool tv = tile < NTILES;

  float S[8], T[8];
  if (AFF){
#pragma unroll
    for (int k = 0; k < 8; ++k){ S[k] = sS[col * 8 + k]; T[k] = sT[col * 8 + k]; }
  }

  const uint4v* x4 = (const uint4v*)xin;

#define INIT8(v)                                                                \
  if (AFF){                                                                     \
    a[0]=fmaxf(bflo((v).x)*S[0]+T[0],0.f); a[1]=fmaxf(bfhi((v).x)*S[1]+T[1],0.f); \
    a[2]=fmaxf(bflo((v).y)*S[2]+T[2],0.f); a[3]=fmaxf(bfhi((v).y)*S[3]+T[3],0.f); \
    a[4]=fmaxf(bflo((v).z)*S[4]+T[4],0.f); a[5]=fmaxf(bfhi((v).z)*S[5]+T[5],0.f); \
    a[6]=fmaxf(bflo((v).w)*S[6]+T[6],0.f); a[7]=fmaxf(bfhi((v).w)*S[7]+T[7],0.f); \
  } else {                                                                      \
    a[0]=bflo((v).x); a[1]=bfhi((v).x); a[2]=bflo((v).y); a[3]=bfhi((v).y);     \
    a[4]=bflo((v).z); a[5]=bfhi((v).z); a[6]=bflo((v).w); a[7]=bfhi((v).w);     \
  }

#define ACC8(v)                                                                 \
  if (AFF){                                                                     \
    a[0]+=fmaxf(bflo((v).x)*S[0]+T[0],0.f); a[1]+=fmaxf(bfhi((v).x)*S[1]+T[1],0.f); \
    a[2]+=fmaxf(bflo((v).y)*S[2]+T[2],0.f); a[3]+=fmaxf(bfhi((v).y)*S[3]+T[3],0.f); \
    a[4]+=fmaxf(bflo((v).z)*S[4]+T[4],0.f); a[5]+=fmaxf(bfhi((v).z)*S[5]+T[5],0.f); \
    a[6]+=fmaxf(bflo((v).w)*S[6]+T[6],0.f); a[7]+=fmaxf(bfhi((v).w)*S[7]+T[7],0.f); \
  } else {                                                                      \
    a[0]+=bflo((v).x); a[1]+=bfhi((v).x); a[2]+=bflo((v).y); a[3]+=bfhi((v).y); \
    a[4]+=bflo((v).z); a[5]+=bfhi((v).z); a[6]+=bflo((v).w); a[7]+=bfhi((v).w); \
  }

  if (tv){
    for (int it = 0; it < 4; ++it){
      int node = tile * 16 + it * 4 + grp;
      int e = deg[node];
      const int* sl = slots + node * MAXDEG;
      float a[8];
      {
        uint4v v = x4[node * 16 + col];
        INIT8(v);
      }
      int j = 0;
      for (; j + 8 <= e; j += 8){
        int i0 = sl[j+0], i1 = sl[j+1], i2 = sl[j+2], i3 = sl[j+3];
        int i4 = sl[j+4], i5 = sl[j+5], i6 = sl[j+6], i7 = sl[j+7];
        uint4v v0 = x4[i0 * 16 + col];
        uint4v v1 = x4[i1 * 16 + col];
        uint4v v2 = x4[i2 * 16 + col];
        uint4v v3 = x4[i3 * 16 + col];
        uint4v v4 = x4[i4 * 16 + col];
        uint4v v5 = x4[i5 * 16 + col];
        uint4v v6 = x4[i6 * 16 + col];
        uint4v v7 = x4[i7 * 16 + col];
        ACC8(v0); ACC8(v1); ACC8(v2); ACC8(v3);
        ACC8(v4); ACC8(v5); ACC8(v6); ACC8(v7);
      }
      for (; j + 4 <= e; j += 4){
        int i0 = sl[j+0], i1 = sl[j+1], i2 = sl[j+2], i3 = sl[j+3];
        uint4v v0 = x4[i0 * 16 + col];
        uint4v v1 = x4[i1 * 16 + col];
        uint4v v2 = x4[i2 * 16 + col];
        uint4v v3 = x4[i3 * 16 + col];
        ACC8(v0); ACC8(v1); ACC8(v2); ACC8(v3);
      }
      for (; j < e; ++j){
        uint4v v = x4[sl[j] * 16 + col];
        ACC8(v);
      }
      uint4v o;
      o.x = pk2(a[0], a[1]); o.y = pk2(a[2], a[3]);
      o.z = pk2(a[4], a[5]); o.w = pk2(a[6], a[7]);
      a4[wave][(it * 4 + grp) * 17 + col] = o;
    }
  }
#undef INIT8
#undef ACC8
  __syncthreads();

  // ---- phase 2: MFMA from the wave-private LDS A-tile ----
  int m = lane & 15, q = lane >> 4;
  f32x4 acc[8];
#pragma unroll
  for (int i = 0; i < 8; ++i) acc[i] = (f32x4)0.f;

#pragma unroll
  for (int kt = 0; kt < 4; ++kt){
    uint4v t = a4[wave][m * 17 + kt * 4 + q];
    short8 af = *(short8*)&t;
#pragma unroll
    for (int to = 0; to < 8; ++to){
      uint4v bw = w4[(to * 16 + m) * 17 + kt * 4 + q];
      acc[to] = __builtin_amdgcn_mfma_f32_16x16x32_bf16(af, *(short8*)&bw, acc[to], 0, 0, 0);
    }
  }

#pragma unroll
  for (int to = 0; to < 8; ++to){
    int colo = to * 16 + m;
    float bc = bias[colo];
    float ls = 0.f, lq = 0.f;
    if (tv){
#pragma unroll
      for (int r = 0; r < 4; ++r){
        float v = acc[to][r] + bc;
        int row = tile * 16 + q * 4 + r;
        __builtin_nontemporal_store(__builtin_bit_cast(ushort, f2bf(v)), Yb + row * 128 + colo);
        ls += v; lq += v * v;
      }
    }
    ls += __shfl_xor(ls, 16); lq += __shfl_xor(lq, 16);
    ls += __shfl_xor(ls, 32); lq += __shfl_xor(lq, 32);
    if (tv && q == 0){ atomicAdd(&ssum[colo], ls); atomicAdd(&ssq[colo], lq); }
  }
  __syncthreads();
  if (threadIdx.x < 128){
    int sb = (blockIdx.x & 7) * 256;
    atomicAdd(&statsOut[sb + threadIdx.x], ssum[threadIdx.x]);
    atomicAdd(&statsOut[sb + 128 + threadIdx.x], ssq[threadIdx.x]);
  }
}

// ---------------- unified GEMM: Y = [relu(affine(A))] @ W^T + bias ----------------
// 512 threads, 8 waves, 1 tile (16 rows) per wave; grid 391.
__global__ __launch_bounds__(512) void gemm_kernel(const ushort* __restrict__ A,
                                                   const ushort* __restrict__ W,
                                                   const float* __restrict__ bias,
                                                   ushort* __restrict__ Yb,
                                                   float* __restrict__ Yf,
                                                   float* __restrict__ statsOut,
                                                   const float* __restrict__ statsIn,
                                                   const float* __restrict__ gA,
                                                   const float* __restrict__ gB,
                                                   const float* __restrict__ bB,
                                                   int mode){
  __shared__ uint4v w4[128 * 17];
  __shared__ float ssum[128];
  __shared__ float ssq[128];
  __shared__ float sS[128];
  __shared__ float sT[128];
  const uint4v* Wg = (const uint4v*)W;
  for (int c = threadIdx.x; c < 2048; c += 512){
    w4[(c >> 4) * 17 + (c & 15)] = Wg[c];
  }
  if (statsIn) bn_params8(statsIn, gA, gB, bB, mode, sS, sT);
  if (threadIdx.x < 128){ ssum[threadIdx.x] = 0.f; ssq[threadIdx.x] = 0.f; }
  __syncthreads();

  int wave = threadIdx.x >> 6;
  int lane = threadIdx.x & 63;
  int m = lane & 15, q = lane >> 4;
  int tile = blockIdx.x * 8 + wave;
  bool tv = tile < NTILES;
  const uint4v* A4 = (const uint4v*)A;

  f32x4 acc[8];
#pragma unroll
  for (int i = 0; i < 8; ++i) acc[i] = (f32x4)0.f;

#pragma unroll
  for (int kt = 0; kt < 4; ++kt){
    short8 af = (short8)0;
    if (tv){
      uint4v t = __builtin_nontemporal_load(A4 + (tile * 16 + m) * 16 + kt * 4 + q);
      if (statsIn){
        int kc = kt * 32 + q * 8;
        uint4v pk;
        pk.x = pk2(fmaxf(bflo(t.x)*sS[kc+0]+sT[kc+0],0.f),
                   fmaxf(bfhi(t.x)*sS[kc+1]+sT[kc+1],0.f));
        pk.y = pk2(fmaxf(bflo(t.y)*sS[kc+2]+sT[kc+2],0.f),
                   fmaxf(bfhi(t.y)*sS[kc+3]+sT[kc+3],0.f));
        pk.z = pk2(fmaxf(bflo(t.z)*sS[kc+4]+sT[kc+4],0.f),
                   fmaxf(bfhi(t.z)*sS[kc+5]+sT[kc+5],0.f));
        pk.w = pk2(fmaxf(bflo(t.w)*sS[kc+6]+sT[kc+6],0.f),
                   fmaxf(bfhi(t.w)*sS[kc+7]+sT[kc+7],0.f));
        t = pk;
      }
      af = *(short8*)&t;
    }
#pragma unroll
    for (int to = 0; to < 8; ++to){
      uint4v bw = w4[(to * 16 + m) * 17 + kt * 4 + q];
      acc[to] = __builtin_amdgcn_mfma_f32_16x16x32_bf16(af, *(short8*)&bw, acc[to], 0, 0, 0);
    }
  }

  bool dost = (statsOut != nullptr);
#pragma unroll
  for (int to = 0; to < 8; ++to){
    int col = to * 16 + m;
    float bc = bias[col];
    float ls = 0.f, lq = 0.f;
    if (tv){
#pragma unroll
      for (int r = 0; r < 4; ++r){
        float v = acc[to][r] + bc;
        int row = tile * 16 + q * 4 + r;
        if (Yb) __builtin_nontemporal_store(__builtin_bit_cast(ushort, f2bf(v)), Yb + row * 128 + col);
        else    __builtin_nontemporal_store(v, Yf + row * 128 + col);
        ls += v; lq += v * v;
      }
    }
    if (dost){
      ls += __shfl_xor(ls, 16); lq += __shfl_xor(lq, 16);
      ls += __shfl_xor(ls, 32); lq += __shfl_xor(lq, 32);
      if (tv && q == 0){ atomicAdd(&ssum[col], ls); atomicAdd(&ssq[col], lq); }
    }
  }
  if (dost){
    __syncthreads();
    if (threadIdx.x < 128){
      int sb = (blockIdx.x & 7) * 256;
      atomicAdd(&statsOut[sb + threadIdx.x], ssum[threadIdx.x]);
      atomicAdd(&statsOut[sb + 128 + threadIdx.x], ssq[threadIdx.x]);
    }
  }
}

extern "C" void kernel_launch(void* const* d_in, const int* in_sizes, int n_in,
                              void* d_out, int out_size, void* d_ws, size_t ws_size,
                              hipStream_t stream) {
  const float* x     = (const float*)d_in[0];
  const int*   ei    = (const int*)d_in[1];
  const float* fc1_w = (const float*)d_in[2];
  const float* fc1_b = (const float*)d_in[3];
  const float* bn1_g = (const float*)d_in[4];
  const float* bn1_b = (const float*)d_in[5];
  const float* fc2_w = (const float*)d_in[6];
  const float* fc2_b = (const float*)d_in[7];
  const float* bn2_g = (const float*)d_in[8];
  const float* bn3_g = (const float*)d_in[10];
  const float* bn3_b = (const float*)d_in[11];
  const float* fc_w  = (const float*)d_in[12];
  const float* fc_b  = (const float*)d_in[13];

  int E = in_sizes[1] / 2;
  const int* srcp = ei;
  const int* dstp = ei + E;

  char* ws = (char*)d_ws;
  int*    cnt    = (int*)(ws + 0);           // N ints (degree)
  float*  stats  = (float*)(ws + 200064);    // 8 slices x 8 sub x 256 floats = 64KB
  int*    pos    = (int*)(ws + 265600);      // E ints
  int*    slots  = (int*)(ws + 3465600);     // N*MAXDEG ints = 12.8 MB
  ushort* wb     = (ushort*)(ws + 16265600); // 147456 bf16
  ushort* xb     = (ushort*)(ws + 16560512); // N*128 bf16
  ushort* y1b    = (ushort*)(ws + 29360512); // N*128 bf16
  ushort* y2b    = (ushort*)(ws + 42160512); // N*128 bf16

  // cast_all also zeroes cnt+stats (contiguous 265600 B at ws start)
  cast_all<<<2048, 256, 0, stream>>>(x, fc1_w, fc2_w, fc_w, xb, wb, (uint*)ws);

  const int EB4 = (E / 4 + 255) / 256 + 1;
  fill1_kernel<<<EB4, 256, 0, stream>>>(dstp, cnt, pos, E);
  fill2_kernel<<<EB4, 256, 0, stream>>>(srcp, dstp, pos, slots, E);

  const int gb = (NTILES + 7) / 8;  // 391 blocks x 8 waves

  for (int i = 0; i < NL; ++i){
    // fused agg + fc1: gather (+bn23 affine for i>0) -> LDS tile -> MFMA -> y1b, stats1
    if (i == 0){
      aggemm_t<false><<<gb, 512, 0, stream>>>(xb, cnt, slots, wb + i * 16384,
                                              fc1_b + i * 128, y1b,
                                              stats + (i * 2) * 2048,
                                              nullptr, nullptr, nullptr, nullptr);
    } else {
      aggemm_t<true><<<gb, 512, 0, stream>>>(y2b, cnt, slots, wb + i * 16384,
                                             fc1_b + i * 128, y1b,
                                             stats + (i * 2) * 2048,
                                             stats + ((i - 1) * 2 + 1) * 2048,
                                             bn2_g + (i - 1) * 128,
                                             bn3_g + (i - 1) * 128,
                                             bn3_b + (i - 1) * 128);
    }
    // fc2: relu(bn1(y1b)) -> y2b (bf16), stats2; bn1 params inline from stats1
    gemm_kernel<<<gb, 512, 0, stream>>>(y1b, wb + 65536 + i * 16384, fc2_b + i * 128,
                                        y2b, nullptr, stats + (i * 2 + 1) * 2048,
                                        stats + (i * 2) * 2048, bn1_g + i * 128,
                                        bn1_b + i * 128, nullptr, 0);
  }

  // classifier: relu(bn3(bn2(y2b)))@fc_w^T + fc_b -> f32 out; bn23 params inline
  gemm_kernel<<<gb, 512, 0, stream>>>(y2b, wb + 131072, fc_b,
                                      nullptr, (float*)d_out, nullptr,
                                      stats + 7 * 2048, bn2_g + 384,
                                      bn3_g + 384, bn3_b + 384, 1);
}